// Round 8
// baseline (812.110 us; speedup 1.0000x reference)
//
#include <hip/hip_runtime.h>

static constexpr int KDIM   = 128;
static constexpr int NEDGES = 20000;
static constexpr int SCAN_CHUNK = 2048;
static constexpr int NRANGE = 8;

using u16 = unsigned short;
using u32 = unsigned int;

// bf16 helpers: load is exact (shift); store is round-to-nearest-even.
__device__ __forceinline__ float bf2f(u32 lo16) { return __uint_as_float(lo16 << 16); }
__device__ __forceinline__ u32 f2bf(float f) {
    u32 x = __float_as_uint(f);
    return (x + 0x7fffu + ((x >> 16) & 1u)) >> 16;
}
__device__ __forceinline__ u32 pack2(float a, float b) { return f2bf(a) | (f2bf(b) << 16); }

// ---------------- tiled GEMM, XCD-swizzled panels (R7 structure) ----------------
// P_bf16[N,NO] = H[N,128] @ W[128,NO]. H is f32 (layer 1) or bf16 (layers 2,3).
// Panel blocks of one row-block land on the same XCD (ids differing by 8
// round-robin to one XCD) so H is HBM-fetched once; perf heuristic only.
template<int NO, bool IN_BF>
__global__ __launch_bounds__(256) void gemm_tile(const void* __restrict__ Hv,
                                                 const float* __restrict__ W,
                                                 u16* __restrict__ P, int N) {
    constexpr int CB = 32;
    constexpr int NPANEL = NO / CB;
    __shared__ float Wl[KDIM * CB];
    const int xcd = blockIdx.x & 7;
    const int idx = blockIdx.x >> 3;
    const int p   = idx & (NPANEL - 1);
    const int rb  = (idx / NPANEL) * 8 + xcd;
    const int cb0 = p * CB;
    for (int i = threadIdx.x; i < KDIM * CB; i += 256) {
        int k = i >> 5, j = i & 31;
        Wl[i] = W[k * NO + cb0 + j];
    }
    __syncthreads();
    int row = rb * 256 + threadIdx.x;
    if (row >= N) return;
    float acc[CB];
#pragma unroll
    for (int j = 0; j < CB; ++j) acc[j] = 0.0f;
#pragma unroll
    for (int k8 = 0; k8 < KDIM / 8; ++k8) {
        float xs[8];
        if constexpr (IN_BF) {
            const uint4 xv = *reinterpret_cast<const uint4*>(
                (const u16*)Hv + (size_t)row * KDIM + k8 * 8);
            xs[0] = bf2f(xv.x & 0xffffu); xs[1] = bf2f(xv.x >> 16);
            xs[2] = bf2f(xv.y & 0xffffu); xs[3] = bf2f(xv.y >> 16);
            xs[4] = bf2f(xv.z & 0xffffu); xs[5] = bf2f(xv.z >> 16);
            xs[6] = bf2f(xv.w & 0xffffu); xs[7] = bf2f(xv.w >> 16);
        } else {
            const float4* xr = reinterpret_cast<const float4*>(
                (const float*)Hv + (size_t)row * KDIM);
            const float4 a = xr[2 * k8], b = xr[2 * k8 + 1];
            xs[0] = a.x; xs[1] = a.y; xs[2] = a.z; xs[3] = a.w;
            xs[4] = b.x; xs[5] = b.y; xs[6] = b.z; xs[7] = b.w;
        }
#pragma unroll
        for (int kk = 0; kk < 8; ++kk) {
            const float* wrow = &Wl[(k8 * 8 + kk) * CB];
#pragma unroll
            for (int j = 0; j < CB; ++j) acc[j] = fmaf(xs[kk], wrow[j], acc[j]);
        }
    }
    u32* pr = reinterpret_cast<u32*>(P + (size_t)row * NO + cb0);
#pragma unroll
    for (int q = 0; q < 4; ++q) {
        uint4 o;
        o.x = pack2(acc[q * 8 + 0], acc[q * 8 + 1]);
        o.y = pack2(acc[q * 8 + 2], acc[q * 8 + 3]);
        o.z = pack2(acc[q * 8 + 4], acc[q * 8 + 5]);
        o.w = pack2(acc[q * 8 + 6], acc[q * 8 + 7]);
        reinterpret_cast<uint4*>(pr)[q] = o;
    }
}

// ---------------- CSR build: histogram, hierarchical scan, fill ----------------
__global__ __launch_bounds__(256) void hist_kernel(const int* __restrict__ vertex,
                                                   const int* __restrict__ edges,
                                                   int* __restrict__ ecnt,
                                                   int* __restrict__ vcnt, int nnz) {
    int i = blockIdx.x * 256 + threadIdx.x;
    if (i >= nnz) return;
    atomicAdd(&ecnt[edges[i]], 1);
    atomicAdd(&vcnt[vertex[i]], 1);
}

__global__ __launch_bounds__(256) void scan_blocksum(const int* __restrict__ cnt,
                                                     int* __restrict__ bsum, int n) {
    __shared__ int sh[256];
    const int base = blockIdx.x * SCAN_CHUNK;
    int s = 0;
#pragma unroll
    for (int k = 0; k < SCAN_CHUNK / 256; ++k) {
        int idx = base + k * 256 + threadIdx.x;
        if (idx < n) s += cnt[idx];
    }
    sh[threadIdx.x] = s;
    __syncthreads();
    for (int d = 128; d > 0; d >>= 1) {
        if (threadIdx.x < d) sh[threadIdx.x] += sh[threadIdx.x + d];
        __syncthreads();
    }
    if (threadIdx.x == 0) bsum[blockIdx.x] = sh[0];
}

__global__ __launch_bounds__(1024) void scan_bsum(int* __restrict__ bsum, int nb) {
    __shared__ int sh[1024];
    const int t = threadIdx.x;
    sh[t] = (t < nb) ? bsum[t] : 0;
    __syncthreads();
    for (int d = 1; d < 1024; d <<= 1) {
        int v = (t >= d) ? sh[t - d] : 0;
        __syncthreads();
        sh[t] += v;
        __syncthreads();
    }
    if (t < nb) bsum[t] = (t == 0) ? 0 : sh[t - 1];
}

template<bool WITH_INV>
__global__ __launch_bounds__(256) void scan_final(const int* __restrict__ cnt,
                                                  const int* __restrict__ bsum,
                                                  int* __restrict__ off,
                                                  int* __restrict__ cur,
                                                  float* __restrict__ inv, int n) {
    __shared__ int sh[256];
    const int t = threadIdx.x;
    const int base = blockIdx.x * SCAN_CHUNK;
    constexpr int EPT = SCAN_CHUNK / 256;
    int loc[EPT];
    int s = 0;
#pragma unroll
    for (int k = 0; k < EPT; ++k) {
        int idx = base + t * EPT + k;
        loc[k] = (idx < n) ? cnt[idx] : 0;
        s += loc[k];
    }
    sh[t] = s;
    __syncthreads();
    for (int d = 1; d < 256; d <<= 1) {
        int v = (t >= d) ? sh[t - d] : 0;
        __syncthreads();
        sh[t] += v;
        __syncthreads();
    }
    int run = bsum[blockIdx.x] + ((t == 0) ? 0 : sh[t - 1]);
#pragma unroll
    for (int k = 0; k < EPT; ++k) {
        int idx = base + t * EPT + k;
        if (idx < n) {
            off[idx] = run;
            cur[idx] = run;
            if (WITH_INV) inv[idx] = 1.0f / fmaxf((float)loc[k], 1.0f);
            run += loc[k];
            if (idx == n - 1) off[n] = run;
        }
    }
}

// Destination-range-partitioned fill (R6): block b covers entry chunk (b>>3),
// writes only targets in range (b&7) -> bucket windows assemble in one L2.
__global__ __launch_bounds__(256) void fill_ranged(const int* __restrict__ vertex,
                                                   const int* __restrict__ edges,
                                                   int* __restrict__ ecur,
                                                   int* __restrict__ vcur,
                                                   int* __restrict__ ebucket,
                                                   int* __restrict__ vbucket,
                                                   int nnz, int E, int N) {
    const int r = blockIdx.x & (NRANGE - 1);
    const int i = (blockIdx.x >> 3) * 256 + threadIdx.x;
    if (i >= nnz) return;
    const int e = edges[i], v = vertex[i];
    const int elo = (int)((long long)r * E / NRANGE);
    const int ehi = (int)((long long)(r + 1) * E / NRANGE);
    const int vlo = (int)((long long)r * N / NRANGE);
    const int vhi = (int)((long long)(r + 1) * N / NRANGE);
    if (e >= elo && e < ehi) ebucket[atomicAdd(&ecur[e], 1)] = v;
    if (v >= vlo && v < vhi) vbucket[atomicAdd(&vcur[v], 1)] = e;
}

// ---------------- edge gather (bf16 in): Xe[e] = mean of P rows ----------------
// One wave per edge. NO=128: lane covers 2 cols (u32 = 2 bf16).
// NO=64: lane covers 1 col. OUT_F32 for the layer-3 direct Xe output.
template<int NO, bool OUT_F32>
__global__ __launch_bounds__(256) void edge_gather_bf(const u16* __restrict__ P,
                                                      const int* __restrict__ ebucket,
                                                      const int* __restrict__ eoff,
                                                      const float* __restrict__ inv,
                                                      void* __restrict__ Xe, int E) {
    int wid = (blockIdx.x * 256 + threadIdx.x) >> 6;
    if (wid >= E) return;
    const int lane = threadIdx.x & 63;
    const int j1 = eoff[wid + 1];
    int j = eoff[wid];
    float acc0 = 0.0f, acc1 = 0.0f;
    if constexpr (NO == 128) {
        for (; j + 2 <= j1; j += 2) {
            int v0 = ebucket[j], v1 = ebucket[j + 1];
            u32 a = *reinterpret_cast<const u32*>(P + (size_t)v0 * 128 + lane * 2);
            u32 b = *reinterpret_cast<const u32*>(P + (size_t)v1 * 128 + lane * 2);
            acc0 += bf2f(a & 0xffffu) + bf2f(b & 0xffffu);
            acc1 += bf2f(a >> 16) + bf2f(b >> 16);
        }
        if (j < j1) {
            u32 a = *reinterpret_cast<const u32*>(P + (size_t)ebucket[j] * 128 + lane * 2);
            acc0 += bf2f(a & 0xffffu);
            acc1 += bf2f(a >> 16);
        }
        const float s = inv[wid];
        acc0 *= s; acc1 *= s;
        if constexpr (OUT_F32) {
            float2 o; o.x = acc0; o.y = acc1;
            *reinterpret_cast<float2*>((float*)Xe + (size_t)wid * 128 + lane * 2) = o;
        } else {
            *reinterpret_cast<u32*>((u16*)Xe + (size_t)wid * 128 + lane * 2) = pack2(acc0, acc1);
        }
    } else {   // NO == 64
        for (; j + 2 <= j1; j += 2) {
            int v0 = ebucket[j], v1 = ebucket[j + 1];
            acc0 += bf2f(P[(size_t)v0 * 64 + lane]) + bf2f(P[(size_t)v1 * 64 + lane]);
        }
        if (j < j1) acc0 += bf2f(P[(size_t)ebucket[j] * 64 + lane]);
        acc0 *= inv[wid];
        if constexpr (OUT_F32) ((float*)Xe)[(size_t)wid * 64 + lane] = acc0;
        else ((u16*)Xe)[(size_t)wid * 64 + lane] = (u16)f2bf(acc0);
    }
}

// ---------------- vertex gather + combine ----------------
// out[v] = relu?((1+eps)*P[v] + sum Xe[e]). One wave per vertex.
// P (bf16) and out may alias row-locally (own row read once at the end).
template<int NO, bool RELU, bool XE_F32, bool OUT_F32>
__global__ __launch_bounds__(256) void vertex_gather_bf(const u16* P,
                                                        const void* __restrict__ Xe,
                                                        const int* __restrict__ vbucket,
                                                        const int* __restrict__ voff,
                                                        const float* __restrict__ eps,
                                                        void* out, int N) {
    int wid = (blockIdx.x * 256 + threadIdx.x) >> 6;
    if (wid >= N) return;
    const int lane = threadIdx.x & 63;
    const int j1 = voff[wid + 1];
    int j = voff[wid];
    float acc0 = 0.0f, acc1 = 0.0f;
    if constexpr (NO == 128) {
        const u16* Xb = (const u16*)Xe;
        for (; j + 2 <= j1; j += 2) {
            int e0 = vbucket[j], e1 = vbucket[j + 1];
            u32 a = *reinterpret_cast<const u32*>(Xb + (size_t)e0 * 128 + lane * 2);
            u32 b = *reinterpret_cast<const u32*>(Xb + (size_t)e1 * 128 + lane * 2);
            acc0 += bf2f(a & 0xffffu) + bf2f(b & 0xffffu);
            acc1 += bf2f(a >> 16) + bf2f(b >> 16);
        }
        if (j < j1) {
            u32 a = *reinterpret_cast<const u32*>(Xb + (size_t)vbucket[j] * 128 + lane * 2);
            acc0 += bf2f(a & 0xffffu);
            acc1 += bf2f(a >> 16);
        }
        const float g = 1.0f + eps[0];
        u32 pp = *reinterpret_cast<const u32*>(P + (size_t)wid * 128 + lane * 2);
        float o0 = fmaf(g, bf2f(pp & 0xffffu), acc0);
        float o1 = fmaf(g, bf2f(pp >> 16), acc1);
        if (RELU) { o0 = fmaxf(o0, 0.0f); o1 = fmaxf(o1, 0.0f); }
        if constexpr (OUT_F32) {
            float2 o; o.x = o0; o.y = o1;
            *reinterpret_cast<float2*>((float*)out + (size_t)wid * 128 + lane * 2) = o;
        } else {
            *reinterpret_cast<u32*>((u16*)out + (size_t)wid * 128 + lane * 2) = pack2(o0, o1);
        }
    } else {   // NO == 64 (layer 3: Xe f32 = outE, out f32 = outV)
        const float* Xf = (const float*)Xe;
        for (; j + 2 <= j1; j += 2) {
            int e0 = vbucket[j], e1 = vbucket[j + 1];
            acc0 += Xf[(size_t)e0 * 64 + lane] + Xf[(size_t)e1 * 64 + lane];
        }
        if (j < j1) acc0 += Xf[(size_t)vbucket[j] * 64 + lane];
        const float g = 1.0f + eps[0];
        float o = fmaf(g, bf2f(P[(size_t)wid * 64 + lane]), acc0);
        if (RELU) o = fmaxf(o, 0.0f);
        ((float*)out)[(size_t)wid * 64 + lane] = o;
    }
}

extern "C" void kernel_launch(void* const* d_in, const int* in_sizes, int n_in,
                              void* d_out, int out_size, void* d_ws, size_t ws_size,
                              hipStream_t stream) {
    const float* X      = (const float*)d_in[0];
    const int*   vertex = (const int*)d_in[1];
    const int*   edges  = (const int*)d_in[2];
    const float* W1     = (const float*)d_in[3];
    const float* W2     = (const float*)d_in[4];
    const float* W3     = (const float*)d_in[5];
    const float* eps1   = (const float*)d_in[6];
    const float* eps2   = (const float*)d_in[7];
    const float* eps3   = (const float*)d_in[8];

    const int N   = in_sizes[0] / KDIM;   // 100000
    const int nnz = in_sizes[1];          // 800000
    const int E   = NEDGES;               // 20000

    float* outV = (float*)d_out;                 // N*64 f32
    float* outE = outV + (size_t)N * 64;         // E*64 f32 (layer-3 Xe)

    const int TPB = 256;
    auto blocks = [](long long t) { return (unsigned)((t + 255) / 256); };
    const int nbE = (E + SCAN_CHUNK - 1) / SCAN_CHUNK;
    const int nbV = (N + SCAN_CHUNK - 1) / SCAN_CHUNK;
    const int nrb  = (N + 255) / 256;
    const int nrb8 = ((nrb + 7) / 8) * 8;
    const unsigned g128 = (unsigned)(nrb8 * 4);
    const unsigned g64  = (unsigned)(nrb8 * 2);

    // ---------------- workspace carve-up (~65 MB) ----------------
    char* ws = (char*)d_ws;
    size_t off = 0;
    auto carve = [&](size_t bytes) { void* p = ws + off; off += (bytes + 255) & ~(size_t)255; return p; };
    u16*   XeBuf   = (u16*)carve((size_t)E * 128 * 2);       // bf16 edge features (layers 1,2)
    float* inv     = (float*)carve((size_t)E * 4);
    int*   ecnt    = (int*)carve((size_t)E * 4);
    int*   eoff    = (int*)carve((size_t)(E + 1) * 4);
    int*   ecur    = (int*)carve((size_t)E * 4);
    int*   vcnt    = (int*)carve((size_t)N * 4);
    int*   voff    = (int*)carve((size_t)(N + 1) * 4);
    int*   vcur    = (int*)carve((size_t)N * 4);
    int*   ebucket = (int*)carve((size_t)nnz * 4);
    int*   vbucket = (int*)carve((size_t)nnz * 4);
    int*   bsumE   = (int*)carve((size_t)1024 * 4);
    int*   bsumV   = (int*)carve((size_t)1024 * 4);
    u16*   bufA    = (u16*)carve((size_t)N * 128 * 2);       // bf16 node features ping
    u16*   bufB    = (u16*)carve((size_t)N * 128 * 2);       // bf16 node features pong

    // ---------------- CSR build (layer-invariant) ----------------
    hipMemsetAsync(ecnt, 0, (size_t)E * 4, stream);
    hipMemsetAsync(vcnt, 0, (size_t)N * 4, stream);
    hist_kernel<<<blocks(nnz), TPB, 0, stream>>>(vertex, edges, ecnt, vcnt, nnz);
    scan_blocksum<<<nbE, TPB, 0, stream>>>(ecnt, bsumE, E);
    scan_blocksum<<<nbV, TPB, 0, stream>>>(vcnt, bsumV, N);
    scan_bsum<<<1, 1024, 0, stream>>>(bsumE, nbE);
    scan_bsum<<<1, 1024, 0, stream>>>(bsumV, nbV);
    scan_final<true><<<nbE, TPB, 0, stream>>>(ecnt, bsumE, eoff, ecur, inv, E);
    scan_final<false><<<nbV, TPB, 0, stream>>>(vcnt, bsumV, voff, vcur, nullptr, N);
    fill_ranged<<<blocks(nnz) * NRANGE, TPB, 0, stream>>>(vertex, edges, ecur, vcur,
                                                          ebucket, vbucket, nnz, E, N);

    // ---- layer 1: X(f32) -> P1 bf16 in bufA; h1 in bufA (in-place) ----
    gemm_tile<128, false><<<g128, TPB, 0, stream>>>(X, W1, bufA, N);
    edge_gather_bf<128, false><<<blocks((long long)E * 64), TPB, 0, stream>>>(bufA, ebucket, eoff, inv, XeBuf, E);
    vertex_gather_bf<128, true, false, false><<<blocks((long long)N * 64), TPB, 0, stream>>>(bufA, XeBuf, vbucket, voff, eps1, bufA, N);

    // ---- layer 2: h1(bufA) -> P2 bf16 in bufB; h2 in bufB (in-place) ----
    gemm_tile<128, true><<<g128, TPB, 0, stream>>>(bufA, W2, bufB, N);
    edge_gather_bf<128, false><<<blocks((long long)E * 64), TPB, 0, stream>>>(bufB, ebucket, eoff, inv, XeBuf, E);
    vertex_gather_bf<128, true, false, false><<<blocks((long long)N * 64), TPB, 0, stream>>>(bufB, XeBuf, vbucket, voff, eps2, bufB, N);

    // ---- layer 3: h2(bufB) -> P3 bf16 in bufA; Xe3 -> outE f32; outV f32 ----
    gemm_tile<64, true><<<g64, TPB, 0, stream>>>(bufB, W3, bufA, N);
    edge_gather_bf<64, true><<<blocks((long long)E * 64), TPB, 0, stream>>>(bufA, ebucket, eoff, inv, outE, E);
    vertex_gather_bf<64, false, true, true><<<blocks((long long)N * 64), TPB, 0, stream>>>(bufA, outE, vbucket, voff, eps3, outV, N);
}

// Round 9
// 553.173 us; speedup vs baseline: 1.4681x; 1.4681x over previous
//
#include <hip/hip_runtime.h>

static constexpr int KDIM   = 128;
static constexpr int NEDGES = 20000;
static constexpr int SCAN_CHUNK = 2048;
static constexpr int NRANGE = 8;

using u16 = unsigned short;
using u32 = unsigned int;
typedef __attribute__((ext_vector_type(8))) short short8;
typedef __attribute__((ext_vector_type(4))) float f32x4;

// bf16 helpers: load is exact (shift); store is round-to-nearest-even.
__device__ __forceinline__ float bf2f(u32 lo16) { return __uint_as_float(lo16 << 16); }
__device__ __forceinline__ u32 f2bf(float f) {
    u32 x = __float_as_uint(f);
    return (x + 0x7fffu + ((x >> 16) & 1u)) >> 16;
}
__device__ __forceinline__ u32 pack2(float a, float b) { return f2bf(a) | (f2bf(b) << 16); }

// ---------------- converters ----------------
__global__ __launch_bounds__(256) void cvtX_kernel(const float* __restrict__ src,
                                                   u16* __restrict__ dst, int n4) {
    int i = blockIdx.x * 256 + threadIdx.x;
    if (i >= n4) return;
    float4 v = reinterpret_cast<const float4*>(src)[i];
    uint2 o;
    o.x = pack2(v.x, v.y);
    o.y = pack2(v.z, v.w);
    reinterpret_cast<uint2*>(dst)[i] = o;
}

__global__ __launch_bounds__(256) void cvtW_kernel(const float* __restrict__ W1,
                                                   const float* __restrict__ W2,
                                                   const float* __restrict__ W3,
                                                   u16* __restrict__ w1,
                                                   u16* __restrict__ w2,
                                                   u16* __restrict__ w3) {
    int i = blockIdx.x * 256 + threadIdx.x;
    if (i < 16384) w1[i] = (u16)f2bf(W1[i]);
    else if (i < 32768) w2[i - 16384] = (u16)f2bf(W2[i - 16384]);
    else if (i < 40960) w3[i - 32768] = (u16)f2bf(W3[i - 32768]);
}

// ---------------- MFMA GEMM: P[N,NO] = H[N,128] @ W[128,NO], all bf16, f32 acc ----
// Block = 4 waves = 128 rows x 32-col panel. W panel staged TRANSPOSED in LDS
// (pad 8 -> 2-way bank conflicts only). A-frags straight from global (8
// contiguous bf16/lane). XCD swizzle: panel blocks of one row-block land on
// the same XCD so H is HBM-fetched once (perf heuristic only).
// Fragment layouts (m89-verified family):
//   A: row=lane&15, k=8*(lane>>4)+j   B: col=lane&15, same k
//   D: col=lane&15, row=4*(lane>>4)+reg
template<int NO>
__global__ __launch_bounds__(256) void gemm_mfma(const u16* __restrict__ H,
                                                 const u16* __restrict__ Wb,
                                                 u16* __restrict__ P, int N) {
    constexpr int NPANEL = NO / 32;
    constexpr int LDK = 136;                 // 128 + 8 pad (bf16 units)
    __shared__ u16 Wt[32 * LDK];
    const int xcd = blockIdx.x & 7;
    const int idx = blockIdx.x >> 3;
    const int p   = idx & (NPANEL - 1);
    const int rb  = (idx / NPANEL) * 8 + xcd;
    const int cb0 = p * 32;
    for (int i = threadIdx.x; i < 32 * 128; i += 256) {
        int k = i >> 5, c = i & 31;
        Wt[c * LDK + k] = Wb[(size_t)k * NO + cb0 + c];
    }
    __syncthreads();
    const int wave = threadIdx.x >> 6;
    const int lane = threadIdx.x & 63;
    const int r0 = rb * 128 + wave * 32;
    const int lrow = lane & 15;
    const int lkb  = lane >> 4;              // 0..3
    int ra0 = min(r0 + lrow, N - 1);         // clamped A rows (stores guarded)
    int ra1 = min(r0 + 16 + lrow, N - 1);
    const u16* h0  = H + (size_t)ra0 * 128 + lkb * 8;
    const u16* h1  = H + (size_t)ra1 * 128 + lkb * 8;
    const u16* wt0 = &Wt[lrow * LDK + lkb * 8];
    const u16* wt1 = &Wt[(16 + lrow) * LDK + lkb * 8];
    f32x4 acc00 = {}, acc01 = {}, acc10 = {}, acc11 = {};
#pragma unroll
    for (int ks = 0; ks < 4; ++ks) {
        short8 a0 = *reinterpret_cast<const short8*>(h0 + ks * 32);
        short8 a1 = *reinterpret_cast<const short8*>(h1 + ks * 32);
        short8 b0 = *reinterpret_cast<const short8*>(wt0 + ks * 32);
        short8 b1 = *reinterpret_cast<const short8*>(wt1 + ks * 32);
        acc00 = __builtin_amdgcn_mfma_f32_16x16x32_bf16(a0, b0, acc00, 0, 0, 0);
        acc01 = __builtin_amdgcn_mfma_f32_16x16x32_bf16(a0, b1, acc01, 0, 0, 0);
        acc10 = __builtin_amdgcn_mfma_f32_16x16x32_bf16(a1, b0, acc10, 0, 0, 0);
        acc11 = __builtin_amdgcn_mfma_f32_16x16x32_bf16(a1, b1, acc11, 0, 0, 0);
    }
#pragma unroll
    for (int reg = 0; reg < 4; ++reg) {
        int row0 = r0 + 4 * lkb + reg;
        int row1 = r0 + 16 + 4 * lkb + reg;
        if (row0 < N) {
            P[(size_t)row0 * NO + cb0 + lrow]      = (u16)f2bf(acc00[reg]);
            P[(size_t)row0 * NO + cb0 + 16 + lrow] = (u16)f2bf(acc01[reg]);
        }
        if (row1 < N) {
            P[(size_t)row1 * NO + cb0 + lrow]      = (u16)f2bf(acc10[reg]);
            P[(size_t)row1 * NO + cb0 + 16 + lrow] = (u16)f2bf(acc11[reg]);
        }
    }
}

// ---------------- CSR build: histogram, hierarchical scan, fill ----------------
__global__ __launch_bounds__(256) void hist_kernel(const int* __restrict__ vertex,
                                                   const int* __restrict__ edges,
                                                   int* __restrict__ ecnt,
                                                   int* __restrict__ vcnt, int nnz) {
    int i = blockIdx.x * 256 + threadIdx.x;
    if (i >= nnz) return;
    atomicAdd(&ecnt[edges[i]], 1);
    atomicAdd(&vcnt[vertex[i]], 1);
}

__global__ __launch_bounds__(256) void scan_blocksum(const int* __restrict__ cnt,
                                                     int* __restrict__ bsum, int n) {
    __shared__ int sh[256];
    const int base = blockIdx.x * SCAN_CHUNK;
    int s = 0;
#pragma unroll
    for (int k = 0; k < SCAN_CHUNK / 256; ++k) {
        int idx = base + k * 256 + threadIdx.x;
        if (idx < n) s += cnt[idx];
    }
    sh[threadIdx.x] = s;
    __syncthreads();
    for (int d = 128; d > 0; d >>= 1) {
        if (threadIdx.x < d) sh[threadIdx.x] += sh[threadIdx.x + d];
        __syncthreads();
    }
    if (threadIdx.x == 0) bsum[blockIdx.x] = sh[0];
}

__global__ __launch_bounds__(1024) void scan_bsum(int* __restrict__ bsum, int nb) {
    __shared__ int sh[1024];
    const int t = threadIdx.x;
    sh[t] = (t < nb) ? bsum[t] : 0;
    __syncthreads();
    for (int d = 1; d < 1024; d <<= 1) {
        int v = (t >= d) ? sh[t - d] : 0;
        __syncthreads();
        sh[t] += v;
        __syncthreads();
    }
    if (t < nb) bsum[t] = (t == 0) ? 0 : sh[t - 1];
}

template<bool WITH_INV>
__global__ __launch_bounds__(256) void scan_final(const int* __restrict__ cnt,
                                                  const int* __restrict__ bsum,
                                                  int* __restrict__ off,
                                                  int* __restrict__ cur,
                                                  float* __restrict__ inv, int n) {
    __shared__ int sh[256];
    const int t = threadIdx.x;
    const int base = blockIdx.x * SCAN_CHUNK;
    constexpr int EPT = SCAN_CHUNK / 256;
    int loc[EPT];
    int s = 0;
#pragma unroll
    for (int k = 0; k < EPT; ++k) {
        int idx = base + t * EPT + k;
        loc[k] = (idx < n) ? cnt[idx] : 0;
        s += loc[k];
    }
    sh[t] = s;
    __syncthreads();
    for (int d = 1; d < 256; d <<= 1) {
        int v = (t >= d) ? sh[t - d] : 0;
        __syncthreads();
        sh[t] += v;
        __syncthreads();
    }
    int run = bsum[blockIdx.x] + ((t == 0) ? 0 : sh[t - 1]);
#pragma unroll
    for (int k = 0; k < EPT; ++k) {
        int idx = base + t * EPT + k;
        if (idx < n) {
            off[idx] = run;
            cur[idx] = run;
            if (WITH_INV) inv[idx] = 1.0f / fmaxf((float)loc[k], 1.0f);
            run += loc[k];
            if (idx == n - 1) off[n] = run;
        }
    }
}

// Destination-range-partitioned fill (R6): block b covers entry chunk (b>>3),
// writes only targets in range (b&7) -> bucket windows assemble in one L2.
__global__ __launch_bounds__(256) void fill_ranged(const int* __restrict__ vertex,
                                                   const int* __restrict__ edges,
                                                   int* __restrict__ ecur,
                                                   int* __restrict__ vcur,
                                                   int* __restrict__ ebucket,
                                                   int* __restrict__ vbucket,
                                                   int nnz, int E, int N) {
    const int r = blockIdx.x & (NRANGE - 1);
    const int i = (blockIdx.x >> 3) * 256 + threadIdx.x;
    if (i >= nnz) return;
    const int e = edges[i], v = vertex[i];
    const int elo = (int)((long long)r * E / NRANGE);
    const int ehi = (int)((long long)(r + 1) * E / NRANGE);
    const int vlo = (int)((long long)r * N / NRANGE);
    const int vhi = (int)((long long)(r + 1) * N / NRANGE);
    if (e >= elo && e < ehi) ebucket[atomicAdd(&ecur[e], 1)] = v;
    if (v >= vlo && v < vhi) vbucket[atomicAdd(&vcur[v], 1)] = e;
}

// ---------------- edge gather (bf16 in): Xe[e] = mean of P rows ----------------
template<int NO, bool OUT_F32>
__global__ __launch_bounds__(256) void edge_gather_bf(const u16* __restrict__ P,
                                                      const int* __restrict__ ebucket,
                                                      const int* __restrict__ eoff,
                                                      const float* __restrict__ inv,
                                                      void* __restrict__ Xe, int E) {
    int wid = (blockIdx.x * 256 + threadIdx.x) >> 6;
    if (wid >= E) return;
    const int lane = threadIdx.x & 63;
    const int j1 = eoff[wid + 1];
    int j = eoff[wid];
    float acc0 = 0.0f, acc1 = 0.0f;
    if constexpr (NO == 128) {
        for (; j + 2 <= j1; j += 2) {
            int v0 = ebucket[j], v1 = ebucket[j + 1];
            u32 a = *reinterpret_cast<const u32*>(P + (size_t)v0 * 128 + lane * 2);
            u32 b = *reinterpret_cast<const u32*>(P + (size_t)v1 * 128 + lane * 2);
            acc0 += bf2f(a & 0xffffu) + bf2f(b & 0xffffu);
            acc1 += bf2f(a >> 16) + bf2f(b >> 16);
        }
        if (j < j1) {
            u32 a = *reinterpret_cast<const u32*>(P + (size_t)ebucket[j] * 128 + lane * 2);
            acc0 += bf2f(a & 0xffffu);
            acc1 += bf2f(a >> 16);
        }
        const float s = inv[wid];
        acc0 *= s; acc1 *= s;
        if constexpr (OUT_F32) {
            float2 o; o.x = acc0; o.y = acc1;
            *reinterpret_cast<float2*>((float*)Xe + (size_t)wid * 128 + lane * 2) = o;
        } else {
            *reinterpret_cast<u32*>((u16*)Xe + (size_t)wid * 128 + lane * 2) = pack2(acc0, acc1);
        }
    } else {   // NO == 64
        for (; j + 2 <= j1; j += 2) {
            int v0 = ebucket[j], v1 = ebucket[j + 1];
            acc0 += bf2f(P[(size_t)v0 * 64 + lane]) + bf2f(P[(size_t)v1 * 64 + lane]);
        }
        if (j < j1) acc0 += bf2f(P[(size_t)ebucket[j] * 64 + lane]);
        acc0 *= inv[wid];
        if constexpr (OUT_F32) ((float*)Xe)[(size_t)wid * 64 + lane] = acc0;
        else ((u16*)Xe)[(size_t)wid * 64 + lane] = (u16)f2bf(acc0);
    }
}

// ---------------- vertex gather + combine ----------------
// out[v] = relu?((1+eps)*P[v] + sum Xe[e]). One wave per vertex.
// P (bf16) and out may alias row-locally (own row read once at the end).
template<int NO, bool RELU, bool XE_F32, bool OUT_F32>
__global__ __launch_bounds__(256) void vertex_gather_bf(const u16* P,
                                                        const void* __restrict__ Xe,
                                                        const int* __restrict__ vbucket,
                                                        const int* __restrict__ voff,
                                                        const float* __restrict__ eps,
                                                        void* out, int N) {
    int wid = (blockIdx.x * 256 + threadIdx.x) >> 6;
    if (wid >= N) return;
    const int lane = threadIdx.x & 63;
    const int j1 = voff[wid + 1];
    int j = voff[wid];
    float acc0 = 0.0f, acc1 = 0.0f;
    if constexpr (NO == 128) {
        const u16* Xb = (const u16*)Xe;
        for (; j + 2 <= j1; j += 2) {
            int e0 = vbucket[j], e1 = vbucket[j + 1];
            u32 a = *reinterpret_cast<const u32*>(Xb + (size_t)e0 * 128 + lane * 2);
            u32 b = *reinterpret_cast<const u32*>(Xb + (size_t)e1 * 128 + lane * 2);
            acc0 += bf2f(a & 0xffffu) + bf2f(b & 0xffffu);
            acc1 += bf2f(a >> 16) + bf2f(b >> 16);
        }
        if (j < j1) {
            u32 a = *reinterpret_cast<const u32*>(Xb + (size_t)vbucket[j] * 128 + lane * 2);
            acc0 += bf2f(a & 0xffffu);
            acc1 += bf2f(a >> 16);
        }
        const float g = 1.0f + eps[0];
        u32 pp = *reinterpret_cast<const u32*>(P + (size_t)wid * 128 + lane * 2);
        float o0 = fmaf(g, bf2f(pp & 0xffffu), acc0);
        float o1 = fmaf(g, bf2f(pp >> 16), acc1);
        if (RELU) { o0 = fmaxf(o0, 0.0f); o1 = fmaxf(o1, 0.0f); }
        if constexpr (OUT_F32) {
            float2 o; o.x = o0; o.y = o1;
            *reinterpret_cast<float2*>((float*)out + (size_t)wid * 128 + lane * 2) = o;
        } else {
            *reinterpret_cast<u32*>((u16*)out + (size_t)wid * 128 + lane * 2) = pack2(o0, o1);
        }
    } else {   // NO == 64 (layer 3: Xe f32 = outE, out f32 = outV)
        const float* Xf = (const float*)Xe;
        for (; j + 2 <= j1; j += 2) {
            int e0 = vbucket[j], e1 = vbucket[j + 1];
            acc0 += Xf[(size_t)e0 * 64 + lane] + Xf[(size_t)e1 * 64 + lane];
        }
        if (j < j1) acc0 += Xf[(size_t)vbucket[j] * 64 + lane];
        const float g = 1.0f + eps[0];
        float o = fmaf(g, bf2f(P[(size_t)wid * 64 + lane]), acc0);
        if (RELU) o = fmaxf(o, 0.0f);
        ((float*)out)[(size_t)wid * 64 + lane] = o;
    }
}

extern "C" void kernel_launch(void* const* d_in, const int* in_sizes, int n_in,
                              void* d_out, int out_size, void* d_ws, size_t ws_size,
                              hipStream_t stream) {
    const float* X      = (const float*)d_in[0];
    const int*   vertex = (const int*)d_in[1];
    const int*   edges  = (const int*)d_in[2];
    const float* W1     = (const float*)d_in[3];
    const float* W2     = (const float*)d_in[4];
    const float* W3     = (const float*)d_in[5];
    const float* eps1   = (const float*)d_in[6];
    const float* eps2   = (const float*)d_in[7];
    const float* eps3   = (const float*)d_in[8];

    const int N   = in_sizes[0] / KDIM;   // 100000
    const int nnz = in_sizes[1];          // 800000
    const int E   = NEDGES;               // 20000

    float* outV = (float*)d_out;                 // N*64 f32
    float* outE = outV + (size_t)N * 64;         // E*64 f32 (layer-3 Xe)

    const int TPB = 256;
    auto blocks = [](long long t) { return (unsigned)((t + 255) / 256); };
    const int nbE = (E + SCAN_CHUNK - 1) / SCAN_CHUNK;
    const int nbV = (N + SCAN_CHUNK - 1) / SCAN_CHUNK;
    const int nrb  = (N + 127) / 128;           // 782 row-blocks of 128
    const int nrb8 = ((nrb + 7) / 8) * 8;       // 784
    const unsigned g128 = (unsigned)(nrb8 * 4); // 4 panels
    const unsigned g64  = (unsigned)(nrb8 * 2); // 2 panels

    // ---------------- workspace carve-up (~63 MB) ----------------
    char* ws = (char*)d_ws;
    size_t off = 0;
    auto carve = [&](size_t bytes) { void* p = ws + off; off += (bytes + 255) & ~(size_t)255; return p; };
    u16*   XeBuf   = (u16*)carve((size_t)E * 128 * 2);
    float* inv     = (float*)carve((size_t)E * 4);
    int*   ecnt    = (int*)carve((size_t)E * 4);
    int*   eoff    = (int*)carve((size_t)(E + 1) * 4);
    int*   ecur    = (int*)carve((size_t)E * 4);
    int*   vcnt    = (int*)carve((size_t)N * 4);
    int*   voff    = (int*)carve((size_t)(N + 1) * 4);
    int*   vcur    = (int*)carve((size_t)N * 4);
    int*   ebucket = (int*)carve((size_t)nnz * 4);
    int*   vbucket = (int*)carve((size_t)nnz * 4);
    int*   bsumE   = (int*)carve((size_t)1024 * 4);
    int*   bsumV   = (int*)carve((size_t)1024 * 4);
    u16*   Wb1     = (u16*)carve((size_t)16384 * 2);
    u16*   Wb2     = (u16*)carve((size_t)16384 * 2);
    u16*   Wb3     = (u16*)carve((size_t)8192 * 2);
    u16*   bufA    = (u16*)carve((size_t)N * 128 * 2);
    u16*   bufB    = (u16*)carve((size_t)N * 128 * 2);

    // ---------------- converters + CSR build (layer-invariant) ----------------
    cvtX_kernel<<<blocks((long long)N * 128 / 4), TPB, 0, stream>>>(X, bufA, N * 32);
    cvtW_kernel<<<160, TPB, 0, stream>>>(W1, W2, W3, Wb1, Wb2, Wb3);
    hipMemsetAsync(ecnt, 0, (size_t)E * 4, stream);
    hipMemsetAsync(vcnt, 0, (size_t)N * 4, stream);
    hist_kernel<<<blocks(nnz), TPB, 0, stream>>>(vertex, edges, ecnt, vcnt, nnz);
    scan_blocksum<<<nbE, TPB, 0, stream>>>(ecnt, bsumE, E);
    scan_blocksum<<<nbV, TPB, 0, stream>>>(vcnt, bsumV, N);
    scan_bsum<<<1, 1024, 0, stream>>>(bsumE, nbE);
    scan_bsum<<<1, 1024, 0, stream>>>(bsumV, nbV);
    scan_final<true><<<nbE, TPB, 0, stream>>>(ecnt, bsumE, eoff, ecur, inv, E);
    scan_final<false><<<nbV, TPB, 0, stream>>>(vcnt, bsumV, voff, vcur, nullptr, N);
    fill_ranged<<<blocks(nnz) * NRANGE, TPB, 0, stream>>>(vertex, edges, ecur, vcur,
                                                          ebucket, vbucket, nnz, E, N);

    // ---- layer 1: Xb(bufA) -> P1 in bufB; h1 in bufB (vg in-place) ----
    gemm_mfma<128><<<g128, TPB, 0, stream>>>(bufA, Wb1, bufB, N);
    edge_gather_bf<128, false><<<blocks((long long)E * 64), TPB, 0, stream>>>(bufB, ebucket, eoff, inv, XeBuf, E);
    vertex_gather_bf<128, true, false, false><<<blocks((long long)N * 64), TPB, 0, stream>>>(bufB, XeBuf, vbucket, voff, eps1, bufB, N);

    // ---- layer 2: h1(bufB) -> P2 in bufA; h2 in bufA (vg in-place) ----
    gemm_mfma<128><<<g128, TPB, 0, stream>>>(bufB, Wb2, bufA, N);
    edge_gather_bf<128, false><<<blocks((long long)E * 64), TPB, 0, stream>>>(bufA, ebucket, eoff, inv, XeBuf, E);
    vertex_gather_bf<128, true, false, false><<<blocks((long long)N * 64), TPB, 0, stream>>>(bufA, XeBuf, vbucket, voff, eps2, bufA, N);

    // ---- layer 3: h2(bufA) -> P3 in bufB (NO=64); Xe3 -> outE f32; outV f32 ----
    gemm_mfma<64><<<g64, TPB, 0, stream>>>(bufA, Wb3, bufB, N);
    edge_gather_bf<64, true><<<blocks((long long)E * 64), TPB, 0, stream>>>(bufB, ebucket, eoff, inv, outE, E);
    vertex_gather_bf<64, false, true, true><<<blocks((long long)N * 64), TPB, 0, stream>>>(bufB, outE, vbucket, voff, eps3, outV, N);
}